// Round 1
// baseline (353.249 us; speedup 1.0000x reference)
//
#include <hip/hip_runtime.h>
#include <hip/hip_bf16.h>

// RecurrentDecoder: B=256,N=128,D=256,Z=64,H=128, pred_len=30
// BN = 32768 independent GRU rows.
// Math restructuring:
//   gi_t = x_t @ W_ih.T + b_ih,  x_t = base_proj + pos_t @ W_pos
//        = G + pos_t @ P2G,  where
//   G   = [h_obs|z] @ (W_in[:320] @ W_ih.T) + (b_in @ W_ih.T + b_ih + fold(b_hh[r,z]))
//   P2G = W_pos @ W_ih.T   (2 x 384)
// Per step only gh = h @ W_hh.T remains as a real matmul.

#define T_LEN 30
#define H_    128
#define G3_   384
#define KIN_  320

typedef float  f32x4 __attribute__((ext_vector_type(4)));
typedef __bf16 b16x8 __attribute__((ext_vector_type(8)));

#define MFMA16(a,b,c) __builtin_amdgcn_mfma_f32_16x16x32_bf16((a),(b),(c),0,0,0)

__device__ __forceinline__ float fast_sigmoid(float x){
  return __builtin_amdgcn_rcpf(1.0f + __builtin_amdgcn_exp2f(-1.4426950408889634f*x));
}
__device__ __forceinline__ float fast_tanh(float x){
  return 1.0f - 2.0f*__builtin_amdgcn_rcpf(1.0f + __builtin_amdgcn_exp2f(2.8853900817779268f*x));
}
__device__ __forceinline__ b16x8 pack8(float4 a, float4 b){
  b16x8 r;
  r[0]=(__bf16)a.x; r[1]=(__bf16)a.y; r[2]=(__bf16)a.z; r[3]=(__bf16)a.w;
  r[4]=(__bf16)b.x; r[5]=(__bf16)b.y; r[6]=(__bf16)b.z; r[7]=(__bf16)b.w;
  return r;
}

// ---- Weight prep 1: WcT[j][k] = sum_m W_in[k][m] * W_ih[j][m]  (bf16, 384x320) ----
__global__ void prep_wc(const float* __restrict__ W_in, const float* __restrict__ W_ih,
                        __bf16* __restrict__ WcT){
  __shared__ float win[H_];
  int k = blockIdx.x;                       // 0..319
  if (threadIdx.x < H_) win[threadIdx.x] = W_in[(size_t)k*H_ + threadIdx.x];
  __syncthreads();
  int j = threadIdx.x;                      // 0..383
  const float* wr = W_ih + (size_t)j*H_;
  float s = 0.f;
  #pragma unroll 8
  for (int m=0;m<H_;m++) s += wr[m]*win[m];
  WcT[(size_t)j*KIN_ + k] = (__bf16)s;
}

// ---- Weight prep 2: cvec[384], P2G[2][384] ----
__global__ void prep_vec(const float* __restrict__ W_in, const float* __restrict__ b_in,
                         const float* __restrict__ W_ih, const float* __restrict__ b_ih,
                         const float* __restrict__ b_hh,
                         float* __restrict__ cvec, float* __restrict__ P2G){
  int j = threadIdx.x;                      // 0..383
  const float* wr = W_ih + (size_t)j*H_;
  float s  = b_ih[j] + (j < 2*H_ ? b_hh[j] : 0.f);   // fold b_hh for r,z gates
  float p0 = 0.f, p1 = 0.f;
  #pragma unroll 8
  for (int m=0;m<H_;m++){
    float w = wr[m];
    s  += b_in[m]*w;
    p0 += W_in[(size_t)KIN_*H_ + m]*w;       // W_pos row 0
    p1 += W_in[(size_t)(KIN_+1)*H_ + m]*w;   // W_pos row 1
  }
  cvec[j] = s; P2G[j] = p0; P2G[G3_ + j] = p1;
}

// ---- Persistent recurrent kernel: 1024 blocks x 512 threads, 32 rows/block ----
__global__ __launch_bounds__(512, 2)
void decoder(const float* __restrict__ h_obs, const float* __restrict__ zin,
             const float* __restrict__ start_pos,
             const float* __restrict__ W_hh, const float* __restrict__ b_hh,
             const float* __restrict__ W_out, const float* __restrict__ b_out,
             const __bf16* __restrict__ WcT, const float* __restrict__ cvec,
             const float* __restrict__ P2G, float* __restrict__ out)
{
  // LDS: prologue base tile [32][328] bf16 (stride 328 elems = 656B, 16B aligned,
  // bank-shift 4/row); steady-state h ping-pong [2][32][152] (stride 304B).
  __shared__ __bf16 smraw[32*328];

  const int tid  = threadIdx.x;
  const int lane = tid & 63;
  const int w    = tid >> 6;        // wave 0..7 owns h-cols [16w,16w+16)
  const int l15  = lane & 15;
  const int lhi  = lane >> 4;       // 0..3
  const int R0   = blockIdx.x << 5; // 32 rows per block
  const int hcol = (w<<4) + l15;
  const int jr = hcol, jz = H_ + hcol, jn = 2*H_ + hcol;

  // ---- stage base tile (32 x 320 f32 -> bf16 LDS) ----
  {
    const float4* src = reinterpret_cast<const float4*>(h_obs) + (size_t)R0*64;
    #pragma unroll
    for (int i=0;i<4;i++){
      int k = tid + (i<<9);
      float4 v = src[k];
      int r = k>>6, c = (k&63)<<2;
      __bf16* d = &smraw[r*328 + c];
      d[0]=(__bf16)v.x; d[1]=(__bf16)v.y; d[2]=(__bf16)v.z; d[3]=(__bf16)v.w;
    }
    const float4* srcz = reinterpret_cast<const float4*>(zin) + (size_t)R0*16;
    {
      int k = tid;
      float4 v = srcz[k];
      int r = k>>4, c = 256 + ((k&15)<<2);
      __bf16* d = &smraw[r*328 + c];
      d[0]=(__bf16)v.x; d[1]=(__bf16)v.y; d[2]=(__bf16)v.z; d[3]=(__bf16)v.w;
    }
  }
  __syncthreads();

  // ---- prologue: G = base @ Wc + cvec, K=320, kept in registers (C-layout) ----
  f32x4 G[3][2];
  {
    float cr = cvec[jr], cz = cvec[jz], cn = cvec[jn];
    G[0][0] = (f32x4){cr,cr,cr,cr}; G[0][1] = G[0][0];
    G[1][0] = (f32x4){cz,cz,cz,cz}; G[1][1] = G[1][0];
    G[2][0] = (f32x4){cn,cn,cn,cn}; G[2][1] = G[2][0];
    #pragma unroll 1
    for (int kk=0; kk<10; kk++){
      const int ko = (kk<<5) + (lhi<<3);
      b16x8 a0 = *reinterpret_cast<const b16x8*>(&smraw[(l15   )*328 + ko]);
      b16x8 a1 = *reinterpret_cast<const b16x8*>(&smraw[(16+l15)*328 + ko]);
      b16x8 br = *reinterpret_cast<const b16x8*>(WcT + (size_t)jr*KIN_ + ko);
      b16x8 bz = *reinterpret_cast<const b16x8*>(WcT + (size_t)jz*KIN_ + ko);
      b16x8 bn = *reinterpret_cast<const b16x8*>(WcT + (size_t)jn*KIN_ + ko);
      G[0][0] = MFMA16(a0, br, G[0][0]); G[0][1] = MFMA16(a1, br, G[0][1]);
      G[1][0] = MFMA16(a0, bz, G[1][0]); G[1][1] = MFMA16(a1, bz, G[1][1]);
      G[2][0] = MFMA16(a0, bn, G[2][0]); G[2][1] = MFMA16(a1, bn, G[2][1]);
    }
  }
  __syncthreads();  // LDS region reused as h ping-pong from here on

  // ---- persistent B-fragments: W_hh.T slices, replicated W_out ----
  b16x8 Bh[3][4];
  #pragma unroll
  for (int kk=0;kk<4;kk++){
    const int ko = (kk<<5) + (lhi<<3);
    { const float* p = W_hh + (size_t)jr*H_ + ko;
      Bh[0][kk] = pack8(*(const float4*)p, *(const float4*)(p+4)); }
    { const float* p = W_hh + (size_t)jz*H_ + ko;
      Bh[1][kk] = pack8(*(const float4*)p, *(const float4*)(p+4)); }
    { const float* p = W_hh + (size_t)jn*H_ + ko;
      Bh[2][kk] = pack8(*(const float4*)p, *(const float4*)(p+4)); }
  }
  const int oc = l15 & 1;           // delta component this lane's column carries
  b16x8 Bo[4];
  #pragma unroll
  for (int kk=0;kk<4;kk++){
    const float* p = W_out + (size_t)oc*H_ + (kk<<5) + (lhi<<3);
    Bo[kk] = pack8(*(const float4*)p, *(const float4*)(p+4));
  }
  const float pgr0 = P2G[jr], pgr1 = P2G[G3_+jr];
  const float pgz0 = P2G[jz], pgz1 = P2G[G3_+jz];
  const float pgn0 = P2G[jn], pgn1 = P2G[G3_+jn];
  const float bhn  = b_hh[2*H_ + hcol];
  const float bo   = b_out[oc];

  // ---- per-lane state: rows r = R0 + m*16 + lhi*4 + q ----
  float posx[2][4], posy[2][4], st[2][4];
  #pragma unroll
  for (int m=0;m<2;m++)
    #pragma unroll
    for (int q=0;q<4;q++){
      int r = R0 + (m<<4) + (lhi<<2) + q;
      posx[m][q] = start_pos[2*r];
      posy[m][q] = start_pos[2*r+1];
    }

  // ---- step 0: h = 0 (gh = 0), writes h1 into buf0 ----
  #pragma unroll
  for (int m=0;m<2;m++)
    #pragma unroll
    for (int q=0;q<4;q++){
      float p0 = posx[m][q], p1 = posy[m][q];
      float rg = fast_sigmoid(G[0][m][q] + p0*pgr0 + p1*pgr1);
      float zg = fast_sigmoid(G[1][m][q] + p0*pgz0 + p1*pgz1);
      float nn = fast_tanh(fmaf(rg, bhn, G[2][m][q] + p0*pgn0 + p1*pgn1));
      float hnew = nn - zg*nn;            // h_prev = 0
      st[m][q] = hnew;
      smraw[((m<<4)+(lhi<<2)+q)*152 + hcol] = (__bf16)hnew;
    }

  int cur = 0;
  #pragma unroll 1
  for (int t=1; t<T_LEN; ++t){
    __syncthreads();
    // read h_t A-fragments; fused delta-MFMA + gh-MFMA
    f32x4 acc00={0,0,0,0},acc01=acc00,acc10=acc00,acc11=acc00,acc20=acc00,acc21=acc00;
    f32x4 d0a=acc00, d1a=acc00;
    #pragma unroll
    for (int kk=0;kk<4;kk++){
      const int ko = (kk<<5)+(lhi<<3);
      b16x8 a0 = *reinterpret_cast<const b16x8*>(&smraw[cur*4864 + (l15   )*152 + ko]);
      b16x8 a1 = *reinterpret_cast<const b16x8*>(&smraw[cur*4864 + (16+l15)*152 + ko]);
      d0a   = MFMA16(a0, Bo[kk],   d0a);
      d1a   = MFMA16(a1, Bo[kk],   d1a);
      acc00 = MFMA16(a0, Bh[0][kk], acc00);
      acc01 = MFMA16(a1, Bh[0][kk], acc01);
      acc10 = MFMA16(a0, Bh[1][kk], acc10);
      acc11 = MFMA16(a1, Bh[1][kk], acc11);
      acc20 = MFMA16(a0, Bh[2][kk], acc20);
      acc21 = MFMA16(a1, Bh[2][kk], acc21);
    }
    // pos += delta (replicated-column trick: 1 shfl_xor gives the other comp)
    #pragma unroll
    for (int m=0;m<2;m++)
      #pragma unroll
      for (int q=0;q<4;q++){
        float dme  = ((m==0)? d0a[q] : d1a[q]) + bo;
        float doth = __shfl_xor(dme, 1);
        posx[m][q] += (oc==0)? dme  : doth;
        posy[m][q] += (oc==0)? doth : dme;
      }
    // emit traj[t-1] = pos_t
    if (w==0 && l15==0){
      #pragma unroll
      for (int m=0;m<2;m++)
        #pragma unroll
        for (int q=0;q<4;q++){
          int r  = R0 + (m<<4) + (lhi<<2) + q;
          int bb = r >> 7, n = r & 127;
          float2 v; v.x = posx[m][q]; v.y = posy[m][q];
          *reinterpret_cast<float2*>(out + (((size_t)(bb*T_LEN + (t-1))<<7) + n)*2) = v;
        }
    }
    // gates -> h_{t+1}
    const int nb = cur ^ 1;
    #pragma unroll
    for (int m=0;m<2;m++)
      #pragma unroll
      for (int q=0;q<4;q++){
        float p0 = posx[m][q], p1 = posy[m][q];
        float ar = (m==0)? acc00[q] : acc01[q];
        float az = (m==0)? acc10[q] : acc11[q];
        float an = (m==0)? acc20[q] : acc21[q];
        float rg = fast_sigmoid(ar + G[0][m][q] + p0*pgr0 + p1*pgr1);
        float zg = fast_sigmoid(az + G[1][m][q] + p0*pgz0 + p1*pgz1);
        float hn = an + bhn;
        float nn = fast_tanh(fmaf(rg, hn, G[2][m][q] + p0*pgn0 + p1*pgn1));
        float hnew = fmaf(zg, st[m][q] - nn, nn);
        st[m][q] = hnew;
        smraw[nb*4864 + ((m<<4)+(lhi<<2)+q)*152 + hcol] = (__bf16)hnew;
      }
    cur = nb;
  }

  // ---- epilogue: t = 30, delta only ----
  __syncthreads();
  {
    f32x4 d0a={0,0,0,0}, d1a={0,0,0,0};
    #pragma unroll
    for (int kk=0;kk<4;kk++){
      const int ko = (kk<<5)+(lhi<<3);
      b16x8 a0 = *reinterpret_cast<const b16x8*>(&smraw[cur*4864 + (l15   )*152 + ko]);
      b16x8 a1 = *reinterpret_cast<const b16x8*>(&smraw[cur*4864 + (16+l15)*152 + ko]);
      d0a = MFMA16(a0, Bo[kk], d0a);
      d1a = MFMA16(a1, Bo[kk], d1a);
    }
    #pragma unroll
    for (int m=0;m<2;m++)
      #pragma unroll
      for (int q=0;q<4;q++){
        float dme  = ((m==0)? d0a[q] : d1a[q]) + bo;
        float doth = __shfl_xor(dme, 1);
        posx[m][q] += (oc==0)? dme  : doth;
        posy[m][q] += (oc==0)? doth : dme;
      }
    if (w==0 && l15==0){
      #pragma unroll
      for (int m=0;m<2;m++)
        #pragma unroll
        for (int q=0;q<4;q++){
          int r  = R0 + (m<<4) + (lhi<<2) + q;
          int bb = r >> 7, n = r & 127;
          float2 v; v.x = posx[m][q]; v.y = posy[m][q];
          *reinterpret_cast<float2*>(out + (((size_t)(bb*T_LEN + (T_LEN-1))<<7) + n)*2) = v;
        }
    }
  }
}

extern "C" void kernel_launch(void* const* d_in, const int* in_sizes, int n_in,
                              void* d_out, int out_size, void* d_ws, size_t ws_size,
                              hipStream_t stream) {
  const float* h_obs     = (const float*)d_in[0];
  const float* z         = (const float*)d_in[1];
  const float* start_pos = (const float*)d_in[2];
  const float* W_in      = (const float*)d_in[3];
  const float* b_in      = (const float*)d_in[4];
  const float* W_ih      = (const float*)d_in[5];
  const float* b_ih      = (const float*)d_in[6];
  const float* W_hh      = (const float*)d_in[7];
  const float* b_hh      = (const float*)d_in[8];
  const float* W_out     = (const float*)d_in[9];
  const float* b_out     = (const float*)d_in[10];
  // pred_len (d_in[11]) is fixed at 30.

  __bf16* WcT = (__bf16*)d_ws;                                  // 384*320*2 B
  float*  cvec = (float*)((char*)d_ws + (size_t)G3_*KIN_*2);    // 384 f32
  float*  P2G  = cvec + G3_;                                    // 2*384 f32

  prep_wc <<<KIN_, G3_, 0, stream>>>(W_in, W_ih, WcT);
  prep_vec<<<1,    G3_, 0, stream>>>(W_in, b_in, W_ih, b_ih, b_hh, cvec, P2G);
  decoder <<<1024, 512, 0, stream>>>(h_obs, z, start_pos, W_hh, b_hh, W_out, b_out,
                                     WcT, cvec, P2G, (float*)d_out);
}

// Round 2
// 309.805 us; speedup vs baseline: 1.1402x; 1.1402x over previous
//
#include <hip/hip_runtime.h>
#include <hip/hip_bf16.h>

// RecurrentDecoder: B=256,N=128,D=256,Z=64,H=128, pred_len=30
// gi_t = G + pos_t @ P2G,  G = [h_obs|z] @ (W_in[:320] @ W_ih.T) + biases
// Per step: gh = h @ W_hh.T (MFMA), gates (VALU/trans), delta = h @ W_out.T.
// exp2 scale constants folded into prepped weights:
//   r,z rows scaled by -log2(e)  -> sigmoid(x) = rcp(1 + exp2(arg))
//   n rows scaled by +2*log2(e)  -> tanh(x)    = 1 - 2*rcp(1 + exp2(arg))

#define T_LEN 30
#define H_    128
#define G3_   384
#define KIN_  320
#define S_    152              // h-buffer row stride in bf16 elems
#define HBYTES (64*S_*2)       // 19456 B per ping-pong buffer
#define TRAJ_OFF (2*HBYTES)    // 38912
#define LDS_BYTES (TRAJ_OFF + T_LEN*64*2*4)  // + 15360 = 54272

#define SCL_RZ -1.44269504088896341f
#define SCL_N   2.88539008177792681f

typedef float  f32x4 __attribute__((ext_vector_type(4)));
typedef __bf16 b16x8 __attribute__((ext_vector_type(8)));

#define MFMA16(a,b,c) __builtin_amdgcn_mfma_f32_16x16x32_bf16((a),(b),(c),0,0,0)

__device__ __forceinline__ b16x8 pack8s(const float* p, float s){
  b16x8 r;
  #pragma unroll
  for (int i=0;i<8;i++) r[i] = (__bf16)(s*p[i]);
  return r;
}

// ---- Weight prep 1: WcT[j][k] = scale_j * sum_m W_in[k][m] * W_ih[j][m] ----
__global__ void prep_wc(const float* __restrict__ W_in, const float* __restrict__ W_ih,
                        __bf16* __restrict__ WcT){
  __shared__ float win[H_];
  int k = blockIdx.x;                       // 0..319
  if (threadIdx.x < H_) win[threadIdx.x] = W_in[(size_t)k*H_ + threadIdx.x];
  __syncthreads();
  int j = threadIdx.x;                      // 0..383
  const float* wr = W_ih + (size_t)j*H_;
  float s = 0.f;
  #pragma unroll 8
  for (int m=0;m<H_;m++) s += wr[m]*win[m];
  float scl = (j < 2*H_) ? SCL_RZ : SCL_N;
  WcT[(size_t)j*KIN_ + k] = (__bf16)(scl*s);
}

// ---- Weight prep 2: cvec[384], P2G[2][384] (scaled) ----
__global__ void prep_vec(const float* __restrict__ W_in, const float* __restrict__ b_in,
                         const float* __restrict__ W_ih, const float* __restrict__ b_ih,
                         const float* __restrict__ b_hh,
                         float* __restrict__ cvec, float* __restrict__ P2G){
  int j = threadIdx.x;                      // 0..383
  const float* wr = W_ih + (size_t)j*H_;
  float s  = b_ih[j] + (j < 2*H_ ? b_hh[j] : 0.f);
  float p0 = 0.f, p1 = 0.f;
  #pragma unroll 8
  for (int m=0;m<H_;m++){
    float w = wr[m];
    s  += b_in[m]*w;
    p0 += W_in[(size_t)KIN_*H_ + m]*w;
    p1 += W_in[(size_t)(KIN_+1)*H_ + m]*w;
  }
  float scl = (j < 2*H_) ? SCL_RZ : SCL_N;
  cvec[j] = scl*s; P2G[j] = scl*p0; P2G[G3_ + j] = scl*p1;
}

// ---- Persistent recurrent kernel: 512 blocks x 512 threads, 64 rows/block ----
__global__ __launch_bounds__(512, 2)
void decoder(const float* __restrict__ h_obs, const float* __restrict__ zin,
             const float* __restrict__ start_pos,
             const float* __restrict__ W_hh, const float* __restrict__ b_hh,
             const float* __restrict__ W_out, const float* __restrict__ b_out,
             const __bf16* __restrict__ WcT, const float* __restrict__ cvec,
             const float* __restrict__ P2G, float* __restrict__ out)
{
  __shared__ __align__(16) char lds[LDS_BYTES];
  __bf16* hbuf = (__bf16*)lds;               // [2][64][S_] ping-pong
  float*  traj = (float*)(lds + TRAJ_OFF);   // [30][64][2]
  __bf16* stg  = (__bf16*)lds;               // [64][328], prologue only (overlaps)

  const int tid  = threadIdx.x;
  const int lane = tid & 63;
  const int w    = tid >> 6;
  const int l15  = lane & 15;
  const int lhi  = lane >> 4;
  const int R0   = blockIdx.x << 6;          // 64 rows per block
  const int hcol = (w<<4) + l15;
  const int jr = hcol, jz = H_ + hcol, jn = 2*H_ + hcol;
  const int oc = l15 & 1;

  // ---- stage base tile (64 x 320 f32 -> bf16 LDS, stride 328) ----
  {
    const float4* src = reinterpret_cast<const float4*>(h_obs) + (size_t)R0*64;
    #pragma unroll
    for (int i=0;i<8;i++){
      int k = tid + (i<<9);
      float4 v = src[k];
      int r = k>>6, c = (k&63)<<2;
      __bf16* d = &stg[r*328 + c];
      d[0]=(__bf16)v.x; d[1]=(__bf16)v.y; d[2]=(__bf16)v.z; d[3]=(__bf16)v.w;
    }
    const float4* srcz = reinterpret_cast<const float4*>(zin) + (size_t)R0*16;
    #pragma unroll
    for (int i=0;i<2;i++){
      int k = tid + (i<<9);
      float4 v = srcz[k];
      int r = k>>4, c = 256 + ((k&15)<<2);
      __bf16* d = &stg[r*328 + c];
      d[0]=(__bf16)v.x; d[1]=(__bf16)v.y; d[2]=(__bf16)v.z; d[3]=(__bf16)v.w;
    }
  }
  __syncthreads();

  // ---- prologue: G[g] = base @ Wc + cvec (scaled), kept in registers ----
  f32x4 G[2][3][2];
  {
    float cr = cvec[jr], cz = cvec[jz], cn = cvec[jn];
    #pragma unroll
    for (int g=0; g<2; g++){
      G[g][0][0] = (f32x4){cr,cr,cr,cr}; G[g][0][1] = G[g][0][0];
      G[g][1][0] = (f32x4){cz,cz,cz,cz}; G[g][1][1] = G[g][1][0];
      G[g][2][0] = (f32x4){cn,cn,cn,cn}; G[g][2][1] = G[g][2][0];
    }
    #pragma unroll 1
    for (int kk=0; kk<10; kk++){
      const int ko = (kk<<5) + (lhi<<3);
      b16x8 br = *reinterpret_cast<const b16x8*>(WcT + (size_t)jr*KIN_ + ko);
      b16x8 bz = *reinterpret_cast<const b16x8*>(WcT + (size_t)jz*KIN_ + ko);
      b16x8 bn = *reinterpret_cast<const b16x8*>(WcT + (size_t)jn*KIN_ + ko);
      #pragma unroll
      for (int g=0; g<2; g++){
        b16x8 a0 = *reinterpret_cast<const b16x8*>(&stg[(g*32   +l15)*328 + ko]);
        b16x8 a1 = *reinterpret_cast<const b16x8*>(&stg[(g*32+16+l15)*328 + ko]);
        G[g][0][0] = MFMA16(a0, br, G[g][0][0]); G[g][0][1] = MFMA16(a1, br, G[g][0][1]);
        G[g][1][0] = MFMA16(a0, bz, G[g][1][0]); G[g][1][1] = MFMA16(a1, bz, G[g][1][1]);
        G[g][2][0] = MFMA16(a0, bn, G[g][2][0]); G[g][2][1] = MFMA16(a1, bn, G[g][2][1]);
      }
    }
  }

  // ---- persistent B-fragments (scaled W_hh.T slices, replicated W_out) ----
  b16x8 Bh[3][4], Bo[4];
  #pragma unroll
  for (int kk=0;kk<4;kk++){
    const int ko = (kk<<5) + (lhi<<3);
    Bh[0][kk] = pack8s(W_hh + (size_t)jr*H_ + ko, SCL_RZ);
    Bh[1][kk] = pack8s(W_hh + (size_t)jz*H_ + ko, SCL_RZ);
    Bh[2][kk] = pack8s(W_hh + (size_t)jn*H_ + ko, SCL_N);
    Bo[kk]    = pack8s(W_out + (size_t)oc*H_ + ko, 1.0f);
  }
  const float pgr0 = P2G[jr], pgr1 = P2G[G3_+jr];
  const float pgz0 = P2G[jz], pgz1 = P2G[G3_+jz];
  const float pgn0 = P2G[jn], pgn1 = P2G[G3_+jn];
  const float bhn  = SCL_N * b_hh[2*H_ + hcol];
  const float bo   = b_out[oc];
  const f32x4 bovec  = (f32x4){bo,bo,bo,bo};
  const f32x4 bhnvec = (f32x4){bhn,bhn,bhn,bhn};

  // ---- per-lane state ----
  float posx[2][2][4], posy[2][2][4], st[2][2][4];
  #pragma unroll
  for (int g=0; g<2; g++)
    #pragma unroll
    for (int m=0;m<2;m++)
      #pragma unroll
      for (int q=0;q<4;q++){
        int r = R0 + (g<<5) + (m<<4) + (lhi<<2) + q;
        posx[g][m][q] = start_pos[2*r];
        posy[g][m][q] = start_pos[2*r+1];
      }

  __syncthreads();   // staging dead; hbuf region live from here

  // ---- step 0: h = 0, write h1 into buf0 ----
  #pragma unroll
  for (int g=0; g<2; g++)
    #pragma unroll
    for (int m=0;m<2;m++)
      #pragma unroll
      for (int q=0;q<4;q++){
        float p0 = posx[g][m][q], p1 = posy[g][m][q];
        float rg = __builtin_amdgcn_rcpf(1.f + __builtin_amdgcn_exp2f(
                     fmaf(p1,pgr1, fmaf(p0,pgr0, G[g][0][m][q]))));
        float zg = __builtin_amdgcn_rcpf(1.f + __builtin_amdgcn_exp2f(
                     fmaf(p1,pgz1, fmaf(p0,pgz0, G[g][1][m][q]))));
        float inn = fmaf(p1,pgn1, fmaf(p0,pgn0, G[g][2][m][q]));
        float nn = fmaf(-2.f, __builtin_amdgcn_rcpf(1.f + __builtin_amdgcn_exp2f(
                     fmaf(rg, bhn, inn))), 1.f);
        float hnew = nn - zg*nn;
        st[g][m][q] = hnew;
        hbuf[((g<<5)+(m<<4)+(lhi<<2)+q)*S_ + hcol] = (__bf16)hnew;
      }

  // precomputed LDS byte offsets
  const unsigned rdbA = (unsigned)(l15*(S_*2) + (lhi<<4));
  const unsigned wrbA = (unsigned)((lhi<<2)*(S_*2) + hcol*2);

  int cur = 0;
  #pragma unroll 1
  for (int t=1; t<T_LEN; ++t){
    __syncthreads();
    const char* rb = lds + cur*HBYTES;
    char*       wb = lds + (cur^1)*HBYTES;

    #pragma unroll
    for (int g=0; g<2; g++){
      const unsigned go = g*(32*S_*2);
      f32x4 ar0, ar1, az0, az1, an0, an1, d0, d1;
      #pragma unroll
      for (int kk=0;kk<4;kk++){
        b16x8 a0 = *reinterpret_cast<const b16x8*>(rb + go + rdbA + kk*64);
        b16x8 a1 = *reinterpret_cast<const b16x8*>(rb + go + rdbA + 16*S_*2 + kk*64);
        if (kk==0){
          d0  = MFMA16(a0, Bo[0],   bovec);  d1  = MFMA16(a1, Bo[0],   bovec);
          ar0 = MFMA16(a0, Bh[0][0], G[g][0][0]); ar1 = MFMA16(a1, Bh[0][0], G[g][0][1]);
          az0 = MFMA16(a0, Bh[1][0], G[g][1][0]); az1 = MFMA16(a1, Bh[1][0], G[g][1][1]);
          an0 = MFMA16(a0, Bh[2][0], bhnvec);     an1 = MFMA16(a1, Bh[2][0], bhnvec);
        } else {
          d0  = MFMA16(a0, Bo[kk],   d0);  d1  = MFMA16(a1, Bo[kk],   d1);
          ar0 = MFMA16(a0, Bh[0][kk], ar0); ar1 = MFMA16(a1, Bh[0][kk], ar1);
          az0 = MFMA16(a0, Bh[1][kk], az0); az1 = MFMA16(a1, Bh[1][kk], az1);
          an0 = MFMA16(a0, Bh[2][kk], an0); an1 = MFMA16(a1, Bh[2][kk], an1);
        }
      }
      // pos += delta
      #pragma unroll
      for (int m=0;m<2;m++)
        #pragma unroll
        for (int q=0;q<4;q++){
          float dme  = (m==0)? d0[q] : d1[q];
          float doth = __shfl_xor(dme, 1);
          posx[g][m][q] += oc ? doth : dme;
          posy[g][m][q] += oc ? dme  : doth;
        }
      // record traj[t-1] in LDS (wave g is the designated writer for group g)
      if (w==g && l15==0){
        #pragma unroll
        for (int m=0;m<2;m++)
          #pragma unroll
          for (int q=0;q<4;q++){
            int rr = (g<<5) + (m<<4) + (lhi<<2) + q;
            float2 v; v.x = posx[g][m][q]; v.y = posy[g][m][q];
            *reinterpret_cast<float2*>(&traj[(t-1)*128 + rr*2]) = v;
          }
      }
      // gates -> h_{t+1}
      #pragma unroll
      for (int m=0;m<2;m++)
        #pragma unroll
        for (int q=0;q<4;q++){
          float p0 = posx[g][m][q], p1 = posy[g][m][q];
          float ar = (m==0)? ar0[q] : ar1[q];
          float az = (m==0)? az0[q] : az1[q];
          float hn = (m==0)? an0[q] : an1[q];
          float rg = __builtin_amdgcn_rcpf(1.f + __builtin_amdgcn_exp2f(
                       fmaf(p1,pgr1, fmaf(p0,pgr0, ar))));
          float zg = __builtin_amdgcn_rcpf(1.f + __builtin_amdgcn_exp2f(
                       fmaf(p1,pgz1, fmaf(p0,pgz0, az))));
          float inn = fmaf(p1,pgn1, fmaf(p0,pgn0, G[g][2][m][q]));
          float nn = fmaf(-2.f, __builtin_amdgcn_rcpf(1.f + __builtin_amdgcn_exp2f(
                       fmaf(rg, hn, inn))), 1.f);
          float hnew = fmaf(zg, st[g][m][q] - nn, nn);
          st[g][m][q] = hnew;
          *reinterpret_cast<__bf16*>(wb + go + wrbA + (m*16+q)*(S_*2)) = (__bf16)hnew;
        }
    }
    cur ^= 1;
  }

  // ---- epilogue: final delta + traj[29] ----
  __syncthreads();
  {
    const char* rb = lds + cur*HBYTES;
    #pragma unroll
    for (int g=0; g<2; g++){
      const unsigned go = g*(32*S_*2);
      f32x4 d0, d1;
      #pragma unroll
      for (int kk=0;kk<4;kk++){
        b16x8 a0 = *reinterpret_cast<const b16x8*>(rb + go + rdbA + kk*64);
        b16x8 a1 = *reinterpret_cast<const b16x8*>(rb + go + rdbA + 16*S_*2 + kk*64);
        if (kk==0){ d0 = MFMA16(a0, Bo[0], bovec); d1 = MFMA16(a1, Bo[0], bovec); }
        else      { d0 = MFMA16(a0, Bo[kk], d0);   d1 = MFMA16(a1, Bo[kk], d1);   }
      }
      #pragma unroll
      for (int m=0;m<2;m++)
        #pragma unroll
        for (int q=0;q<4;q++){
          float dme  = (m==0)? d0[q] : d1[q];
          float doth = __shfl_xor(dme, 1);
          posx[g][m][q] += oc ? doth : dme;
          posy[g][m][q] += oc ? dme  : doth;
        }
      if (w==g && l15==0){
        #pragma unroll
        for (int m=0;m<2;m++)
          #pragma unroll
          for (int q=0;q<4;q++){
            int rr = (g<<5) + (m<<4) + (lhi<<2) + q;
            float2 v; v.x = posx[g][m][q]; v.y = posy[g][m][q];
            *reinterpret_cast<float2*>(&traj[(T_LEN-1)*128 + rr*2]) = v;
          }
      }
    }
  }

  // ---- bulk trajectory store (coalesced) ----
  __syncthreads();
  {
    const size_t ob  = ((size_t)(R0>>7)*T_LEN)<<8;   // (b*30)*256 floats
    const int    n02 = (R0 & 127)<<1;
    for (int i=tid; i<T_LEN*128; i+=512){
      int tt = i>>7, j = i&127;
      out[ob + (size_t)tt*256 + n02 + j] = traj[i];
    }
  }
}

extern "C" void kernel_launch(void* const* d_in, const int* in_sizes, int n_in,
                              void* d_out, int out_size, void* d_ws, size_t ws_size,
                              hipStream_t stream) {
  const float* h_obs     = (const float*)d_in[0];
  const float* z         = (const float*)d_in[1];
  const float* start_pos = (const float*)d_in[2];
  const float* W_in      = (const float*)d_in[3];
  const float* b_in      = (const float*)d_in[4];
  const float* W_ih      = (const float*)d_in[5];
  const float* b_ih      = (const float*)d_in[6];
  const float* W_hh      = (const float*)d_in[7];
  const float* b_hh      = (const float*)d_in[8];
  const float* W_out     = (const float*)d_in[9];
  const float* b_out     = (const float*)d_in[10];
  // pred_len (d_in[11]) fixed at 30.

  __bf16* WcT  = (__bf16*)d_ws;                                 // 384*320*2 B
  float*  cvec = (float*)((char*)d_ws + (size_t)G3_*KIN_*2);    // 384 f32
  float*  P2G  = cvec + G3_;                                    // 2*384 f32

  prep_wc <<<KIN_, G3_, 0, stream>>>(W_in, W_ih, WcT);
  prep_vec<<<1,    G3_, 0, stream>>>(W_in, b_in, W_ih, b_ih, b_hh, cvec, P2G);
  decoder <<<512, 512, 0, stream>>>(h_obs, z, start_pos, W_hh, b_hh, W_out, b_out,
                                    WcT, cvec, P2G, (float*)d_out);
}